// Round 10
// baseline (273.198 us; speedup 1.0000x reference)
//
#include <hip/hip_runtime.h>
#include <hip/hip_cooperative_groups.h>
#include <math.h>

namespace cg = cooperative_groups;

#define NDIM 128
#define NHID 512
#define NEXPERT 64
#define NTOK 1024
#define NPAIR (NTOK * 2)
#define NBLK 256

typedef __attribute__((ext_vector_type(8))) short short8_t;
typedef __attribute__((ext_vector_type(4))) float f32x4;

__device__ __forceinline__ float gelu_f(float v) {
    return 0.5f * v * (1.0f + erff(v * 0.7071067811865476f));
}
__device__ __forceinline__ unsigned short f2bf(float f) {
    union { float f; unsigned u; } v; v.f = f;
    unsigned r = v.u + 0x7FFFu + ((v.u >> 16) & 1u);
    return (unsigned short)(r >> 16);
}
__device__ __forceinline__ float bf2f(unsigned short h) {
    union { unsigned u; float f; } v; v.u = ((unsigned)h) << 16;
    return v.f;
}
__device__ __forceinline__ void split3(float f, short& ho, short& mo, short& lo) {
    const unsigned short h = f2bf(f);
    const float r1 = f - bf2f(h);
    const unsigned short m = f2bf(r1);
    const unsigned short l = f2bf(r1 - bf2f(m));
    ho = (short)h; mo = (short)m; lo = (short)l;
}

// ---- workspace map (aliasing checked against phase order) ----
struct WSMap {
    unsigned short *G1h, *G1m, *G1l, *G2h, *G2m, *G2l;
    unsigned short *Xh, *Xm, *Xl, *Hh, *Hm, *Hl;
    float* h2; unsigned short* tbuf; float* pbuf;
    int* eidx; float* wval; int* elist; int* ecnt;
};
__device__ __host__ __forceinline__ WSMap make_ws(char* ws) {
    WSMap m;
    m.G1h = (unsigned short*)(ws);
    m.G1m = (unsigned short*)(ws + 131072);
    m.G1l = (unsigned short*)(ws + 262144);
    m.G2h = (unsigned short*)(ws + 524288);
    m.G2m = (unsigned short*)(ws + 1048576);
    m.G2l = (unsigned short*)(ws + 1572864);
    m.Xh  = (unsigned short*)(ws + (2ull << 20));
    m.Xm  = (unsigned short*)(ws + (2ull << 20) + 262144);
    m.Xl  = (unsigned short*)(ws + (2ull << 20) + 524288);
    m.Hh  = (unsigned short*)(ws + (3ull << 20));
    m.Hm  = (unsigned short*)(ws + (4ull << 20));
    m.Hl  = (unsigned short*)(ws + (5ull << 20));
    m.h2  = (float*)(ws + (6ull << 20));
    m.tbuf = (unsigned short*)(ws);               // aliases G (dead after gate2)
    m.pbuf = (float*)(ws + (3ull << 20));         // aliases H + h2[6,7M) (dead)
    m.eidx  = (int*)  (ws + (8ull << 20));
    m.wval  = (float*)(ws + (8ull << 20) + 8192);
    m.elist = (int*)  (ws + (8ull << 20) + 16384);
    m.ecnt  = (int*)  (ws + (8ull << 20) + 16384 + NEXPERT * NPAIR * 4);
    return m;
}

#define SMEM_BYTES 41600

// ---------------- phase bodies (bit-identical math to R8) ----------------

__device__ __forceinline__ void phase_decomp(
        int u, char* smem, int j, const float* __restrict__ x,
        const float* __restrict__ gw1, const float* __restrict__ gw2,
        const WSMap& W) {
    __syncthreads();
    if (u < 80) {
        float (*T)[65] = (float (*)[65])smem;
        const float* src; unsigned short *Dh, *Dm, *Dl; int k0, n0, Kd;
        if (u < 16) { src = gw1; Dh = W.G1h; Dm = W.G1m; Dl = W.G1l;
                      k0 = (u >> 3) * 64; n0 = (u & 7) * 64; Kd = 128; }
        else { const int v = u - 16; src = gw2; Dh = W.G2h; Dm = W.G2m; Dl = W.G2l;
               k0 = (v >> 3) * 64; n0 = (v & 7) * 64; Kd = 512; }
#pragma unroll
        for (int q = 0; q < 4; ++q) {
            const int idx = j + 256 * q;
            const int kr = idx >> 4, c4 = idx & 15;
            float4 v = *(const float4*)(src + (size_t)(k0 + kr) * NHID + n0 + c4 * 4);
            T[kr][c4 * 4 + 0] = v.x; T[kr][c4 * 4 + 1] = v.y;
            T[kr][c4 * 4 + 2] = v.z; T[kr][c4 * 4 + 3] = v.w;
        }
        __syncthreads();
#pragma unroll
        for (int q = 0; q < 4; ++q) {
            const int idx = j + 256 * q;
            const int n = idx >> 4, k4 = idx & 15;
            short4 sh, sm, sl;
#pragma unroll
            for (int qq = 0; qq < 4; ++qq)
                split3(T[k4 * 4 + qq][n], (&sh.x)[qq], (&sm.x)[qq], (&sl.x)[qq]);
            const size_t o = (size_t)(n0 + n) * Kd + k0 + k4 * 4;
            *(short4*)(Dh + o) = sh;
            *(short4*)(Dm + o) = sm;
            *(short4*)(Dl + o) = sl;
        }
    } else {
        const int r0 = (u - 80) * 64;
#pragma unroll
        for (int q = 0; q < 8; ++q) {
            const int idx = j + 256 * q;
            const int row = idx >> 5, c4 = idx & 31;
            float4 v = *(const float4*)(x + (size_t)(r0 + row) * NDIM + c4 * 4);
            short4 sh, sm, sl;
#pragma unroll
            for (int qq = 0; qq < 4; ++qq)
                split3((&v.x)[qq], (&sh.x)[qq], (&sm.x)[qq], (&sl.x)[qq]);
            const size_t o = (size_t)(r0 + row) * NDIM + c4 * 4;
            *(short4*)(W.Xh + o) = sh;
            *(short4*)(W.Xm + o) = sm;
            *(short4*)(W.Xl + o) = sl;
        }
    }
}

// split-bf16 gating GEMM. A planes [M][K], B planes [n][K].
// EPI 0: write 3 bf16 planes; EPI 1: write f32.
template <int K, int EPI>
__device__ __forceinline__ void gatemm_phase(
        int u, char* smem, int j,
        const unsigned short* __restrict__ Ahp, const unsigned short* __restrict__ Amp,
        const unsigned short* __restrict__ Alp,
        const unsigned short* __restrict__ Bhp, const unsigned short* __restrict__ Bmp,
        const unsigned short* __restrict__ Blp,
        const float* __restrict__ bias, float* __restrict__ Cf,
        unsigned short* __restrict__ Chp, unsigned short* __restrict__ Cmp,
        unsigned short* __restrict__ Clp) {
    short (*Ahs)[32][72] = (short (*)[32][72])smem;
    short (*Bss)[64][72] = (short (*)[64][72])(smem + 13824);
    const int m0 = (u >> 3) * 32, n0 = (u & 7) * 64;
    const int w = j >> 6, lane = j & 63;
    const int mt = w & 1, npair = w >> 1;
    const int lrow = lane & 15, lseg = lane >> 4;
    f32x4 acc[2];
    acc[0] = (f32x4){0.f, 0.f, 0.f, 0.f};
    acc[1] = (f32x4){0.f, 0.f, 0.f, 0.f};
    for (int kc = 0; kc < K; kc += 64) {
        __syncthreads();
        {
            const int row = j >> 3, c8 = j & 7;
            const size_t o = (size_t)(m0 + row) * K + kc + c8 * 8;
            *(short8_t*)&Ahs[0][row][c8 * 8] = *(const short8_t*)(Ahp + o);
            *(short8_t*)&Ahs[1][row][c8 * 8] = *(const short8_t*)(Amp + o);
            *(short8_t*)&Ahs[2][row][c8 * 8] = *(const short8_t*)(Alp + o);
        }
#pragma unroll
        for (int q = 0; q < 2; ++q) {
            const int idx = j + 256 * q;
            const int nr = idx >> 3, c8 = idx & 7;
            const size_t o = (size_t)(n0 + nr) * K + kc + c8 * 8;
            *(short8_t*)&Bss[0][nr][c8 * 8] = *(const short8_t*)(Bhp + o);
            *(short8_t*)&Bss[1][nr][c8 * 8] = *(const short8_t*)(Bmp + o);
            *(short8_t*)&Bss[2][nr][c8 * 8] = *(const short8_t*)(Blp + o);
        }
        __syncthreads();
#pragma unroll
        for (int ks = 0; ks < 2; ++ks) {
            const int ko = ks * 32 + lseg * 8;
            short8_t ah = *(short8_t*)&Ahs[0][mt * 16 + lrow][ko];
            short8_t am = *(short8_t*)&Ahs[1][mt * 16 + lrow][ko];
            short8_t al = *(short8_t*)&Ahs[2][mt * 16 + lrow][ko];
#pragma unroll
            for (int nt = 0; nt < 2; ++nt) {
                const int nr = (npair * 2 + nt) * 16 + lrow;
                short8_t bh = *(short8_t*)&Bss[0][nr][ko];
                short8_t bm = *(short8_t*)&Bss[1][nr][ko];
                short8_t bl = *(short8_t*)&Bss[2][nr][ko];
                acc[nt] = __builtin_amdgcn_mfma_f32_16x16x32_bf16(ah, bh, acc[nt], 0, 0, 0);
                acc[nt] = __builtin_amdgcn_mfma_f32_16x16x32_bf16(am, bh, acc[nt], 0, 0, 0);
                acc[nt] = __builtin_amdgcn_mfma_f32_16x16x32_bf16(ah, bm, acc[nt], 0, 0, 0);
                acc[nt] = __builtin_amdgcn_mfma_f32_16x16x32_bf16(al, bh, acc[nt], 0, 0, 0);
                acc[nt] = __builtin_amdgcn_mfma_f32_16x16x32_bf16(ah, bl, acc[nt], 0, 0, 0);
                acc[nt] = __builtin_amdgcn_mfma_f32_16x16x32_bf16(am, bm, acc[nt], 0, 0, 0);
            }
        }
    }
#pragma unroll
    for (int nt = 0; nt < 2; ++nt) {
        const int col = n0 + (npair * 2 + nt) * 16 + lrow;
        const float bb = bias[col];
#pragma unroll
        for (int r = 0; r < 4; ++r) {
            const int row = m0 + mt * 16 + lseg * 4 + r;
            const float h = gelu_f(acc[nt][r] + bb);
            if (EPI == 0) {
                short hh, hm, hl;
                split3(h, hh, hm, hl);
                const size_t o = (size_t)row * NHID + col;
                Chp[o] = (unsigned short)hh; Cmp[o] = (unsigned short)hm;
                Clp[o] = (unsigned short)hl;
            } else {
                Cf[(size_t)row * NHID + col] = h;
            }
        }
    }
}

__device__ __forceinline__ void phase_gate3(
        int u, char* smem, int j, const float* __restrict__ gw3,
        const float* __restrict__ gb3, const WSMap& W) {
    float (*hs)[132] = (float (*)[132])smem;
    float (*gs)[72]  = (float (*)[72])(smem + 4224);
    const int lane = j & 63;
    const int w = j >> 6;
    const int t0 = u * 8;
    float acc[2] = {0.f, 0.f};
    for (int k0 = 0; k0 < NHID; k0 += 128) {
        __syncthreads();
        {
            const int tok = j >> 5, c4 = j & 31;
            *(float4*)&hs[tok][c4 * 4] =
                *(const float4*)(W.h2 + (size_t)(t0 + tok) * NHID + k0 + c4 * 4);
        }
#pragma unroll
        for (int q = 0; q < 8; ++q) {
            const int idx = j + 256 * q;
            const int kk = idx >> 4, c4 = idx & 15;
            *(float4*)&gs[kk][c4 * 4] =
                *(const float4*)(gw3 + (size_t)(k0 + kk) * NEXPERT + c4 * 4);
        }
        __syncthreads();
        for (int kk = 0; kk < 128; ++kk) {
            const float g = gs[kk][lane];
            acc[0] += hs[w * 2][kk] * g;
            acc[1] += hs[w * 2 + 1][kk] * g;
        }
    }
    const float bias = gb3[lane];
#pragma unroll
    for (int i = 0; i < 2; ++i) {
        const int t = t0 + w * 2 + i;
        float s = 1.f / (1.f + expf(-(acc[i] + bias)));
        float v = s; int ix = lane;
#pragma unroll
        for (int off = 32; off >= 1; off >>= 1) {
            float ov = __shfl_xor(v, off);
            int oi = __shfl_xor(ix, off);
            if (ov > v || (ov == v && oi < ix)) { v = ov; ix = oi; }
        }
        const float v0 = v; const int i0 = ix;
        float v2 = (lane == i0) ? -1.f : s; int ix2 = lane;
#pragma unroll
        for (int off = 32; off >= 1; off >>= 1) {
            float ov = __shfl_xor(v2, off);
            int oi = __shfl_xor(ix2, off);
            if (ov > v2 || (ov == v2 && oi < ix2)) { v2 = ov; ix2 = oi; }
        }
        if (lane == 0) {
            float inv = 1.f / (v0 + v2);
            W.eidx[t * 2] = i0;  W.eidx[t * 2 + 1] = ix2;
            W.wval[t * 2] = v0 * inv;  W.wval[t * 2 + 1] = v2 * inv;
        }
    }
}

__device__ __forceinline__ void phase_lists(
        int u, char* smem, int j, const WSMap& W) {
    int* cnts = (int*)smem;
    __syncthreads();
    int my[8];
    int mc = 0;
#pragma unroll
    for (int q = 0; q < 8; ++q) {
        int i = j * 8 + q;
        if (W.eidx[i] == u) my[mc++] = i;
    }
    cnts[j] = mc;
    __syncthreads();
    for (int off = 1; off < 256; off <<= 1) {
        int other = (j >= off) ? cnts[j - off] : 0;
        __syncthreads();
        cnts[j] += other;
        __syncthreads();
    }
    const int base = cnts[j] - mc;
    for (int q = 0; q < mc; ++q) W.elist[u * NPAIR + base + q] = my[q];
    if (j == 255) W.ecnt[u] = cnts[255];
}

__device__ __forceinline__ void phase_l1(
        int u, char* smem, int j, const float* __restrict__ x,
        const float* __restrict__ W1, const float* __restrict__ B1,
        const WSMap& W) {
    char* Asc = smem;
    char* Bsc = smem + 8704;
    int* prs = (int*)(smem + 26112);
    const int lane = j & 63;
    const int w = j >> 6;
    const int e = u >> 3;
    const int f0 = (u & 7) * 64;
    const int n = W.ecnt[e];
    const int* le = W.elist + e * NPAIR;
    const float* W1e = W1 + (size_t)e * NHID * NDIM;
    __syncthreads();
    for (int idx = j; idx < 2048; idx += 256) {
        const int f = idx >> 5, c4 = idx & 31;
        float4 v = *(const float4*)(W1e + (size_t)(f0 + f) * NDIM + c4 * 4);
        short4 s; s.x = (short)f2bf(v.x); s.y = (short)f2bf(v.y);
        s.z = (short)f2bf(v.z); s.w = (short)f2bf(v.w);
        *(short4*)(Bsc + f * 272 + c4 * 8) = s;
    }
    const float bbias = B1[e * NHID + f0 + w * 16 + (lane & 15)];
    for (int bt = 0; bt * 32 < n; ++bt) {
        const int nb = min(32, n - bt * 32);
        __syncthreads();
        if (j < 32) prs[j] = (j < nb) ? le[bt * 32 + j] : -1;
        __syncthreads();
        for (int idx = j; idx < 1024; idx += 256) {
            const int tok = idx >> 5, c4 = idx & 31;
            const int pr = prs[tok];
            float4 v = make_float4(0.f, 0.f, 0.f, 0.f);
            if (pr >= 0) v = ((const float4*)x)[(size_t)(pr >> 1) * 32 + c4];
            short4 s; s.x = (short)f2bf(v.x); s.y = (short)f2bf(v.y);
            s.z = (short)f2bf(v.z); s.w = (short)f2bf(v.w);
            *(short4*)(Asc + tok * 272 + c4 * 8) = s;
        }
        __syncthreads();
        f32x4 acc[2];
        acc[0] = (f32x4){0.f, 0.f, 0.f, 0.f};
        acc[1] = (f32x4){0.f, 0.f, 0.f, 0.f};
        const int acol = ((lane >> 4) << 4);
        const int brow = w * 16 + (lane & 15);
#pragma unroll
        for (int ks = 0; ks < 4; ++ks) {
            short8_t b = *(short8_t*)(Bsc + brow * 272 + ks * 64 + acol);
#pragma unroll
            for (int mt = 0; mt < 2; ++mt) {
                short8_t a = *(short8_t*)(Asc + (mt * 16 + (lane & 15)) * 272 + ks * 64 + acol);
                acc[mt] = __builtin_amdgcn_mfma_f32_16x16x32_bf16(a, b, acc[mt], 0, 0, 0);
            }
        }
        const int fcol = f0 + w * 16 + (lane & 15);
#pragma unroll
        for (int mt = 0; mt < 2; ++mt) {
#pragma unroll
            for (int r = 0; r < 4; ++r) {
                const int tok = mt * 16 + ((lane >> 4) << 2) + r;
                const int pr = prs[tok];
                if (pr >= 0)
                    W.tbuf[(size_t)pr * NHID + fcol] = f2bf(gelu_f(acc[mt][r] + bbias));
            }
        }
    }
}

__device__ __forceinline__ void phase_l2(
        int u, char* smem, int j, const float* __restrict__ W2,
        const WSMap& W) {
    char* Asc = smem;
    char* Bsc = smem + 8704;
    int* prs = (int*)(smem + 26112);
    const int lane = j & 63;
    const int w = j >> 6;
    const int e = u >> 3;
    const int d0 = ((u >> 2) & 1) * 64;
    const int kz = u & 3;
    const int k0 = kz * 128;
    const int n = W.ecnt[e];
    const int* le = W.elist + e * NPAIR;
    const float* W2e = W2 + (size_t)e * NDIM * NHID;
    __syncthreads();
    for (int idx = j; idx < 2048; idx += 256) {
        const int d = idx >> 5, c4 = idx & 31;
        float4 v = *(const float4*)(W2e + (size_t)(d0 + d) * NHID + k0 + c4 * 4);
        short4 s; s.x = (short)f2bf(v.x); s.y = (short)f2bf(v.y);
        s.z = (short)f2bf(v.z); s.w = (short)f2bf(v.w);
        *(short4*)(Bsc + d * 272 + c4 * 8) = s;
    }
    float* pz = W.pbuf + (size_t)kz * NPAIR * NDIM;
    for (int bt = 0; bt * 32 < n; ++bt) {
        const int nb = min(32, n - bt * 32);
        __syncthreads();
        if (j < 32) prs[j] = (j < nb) ? le[bt * 32 + j] : -1;
        __syncthreads();
        for (int idx = j; idx < 512; idx += 256) {
            const int tok = idx >> 4, c8 = idx & 15;
            const int pr = prs[tok];
            short8_t v = (short8_t)(short)0;
            if (pr >= 0) v = *(const short8_t*)(W.tbuf + (size_t)pr * NHID + k0 + c8 * 8);
            *(short8_t*)(Asc + tok * 272 + c8 * 16) = v;
        }
        __syncthreads();
        f32x4 acc[2];
        acc[0] = (f32x4){0.f, 0.f, 0.f, 0.f};
        acc[1] = (f32x4){0.f, 0.f, 0.f, 0.f};
        const int acol = ((lane >> 4) << 4);
        const int brow = w * 16 + (lane & 15);
#pragma unroll
        for (int ks = 0; ks < 4; ++ks) {
            short8_t b = *(short8_t*)(Bsc + brow * 272 + ks * 64 + acol);
#pragma unroll
            for (int mt = 0; mt < 2; ++mt) {
                short8_t a = *(short8_t*)(Asc + (mt * 16 + (lane & 15)) * 272 + ks * 64 + acol);
                acc[mt] = __builtin_amdgcn_mfma_f32_16x16x32_bf16(a, b, acc[mt], 0, 0, 0);
            }
        }
        const int dcol = d0 + w * 16 + (lane & 15);
#pragma unroll
        for (int mt = 0; mt < 2; ++mt) {
#pragma unroll
            for (int r = 0; r < 4; ++r) {
                const int tok = mt * 16 + ((lane >> 4) << 2) + r;
                const int pr = prs[tok];
                if (pr >= 0) pz[(size_t)pr * NDIM + dcol] = acc[mt][r];
            }
        }
    }
}

__device__ __forceinline__ void phase_combine(
        int u, int j, const float* __restrict__ B2, float* __restrict__ out,
        const WSMap& W) {
    const int i = u * 256 + j;
    const int t = i >> 7, d = i & (NDIM - 1);
    const int KS = NPAIR * NDIM;
    float y[2];
#pragma unroll
    for (int k = 0; k < 2; ++k) {
        const int p = t * 2 + k;
        float s = W.pbuf[p * NDIM + d] + W.pbuf[KS + p * NDIM + d]
                + W.pbuf[2 * KS + p * NDIM + d] + W.pbuf[3 * KS + p * NDIM + d]
                + B2[W.eidx[p] * NDIM + d];
        y[k] = gelu_f(s);
    }
    out[i] = W.wval[t * 2] * y[0] + W.wval[t * 2 + 1] * y[1];
}

// ---------------- cooperative mega-kernel ----------------
__global__ __launch_bounds__(256, 2) void moe_mega(
        const float* __restrict__ x, const float* __restrict__ gw1,
        const float* __restrict__ gb1, const float* __restrict__ gw2,
        const float* __restrict__ gb2, const float* __restrict__ gw3,
        const float* __restrict__ gb3, const float* __restrict__ W1,
        const float* __restrict__ B1, const float* __restrict__ W2,
        const float* __restrict__ B2, float* __restrict__ out,
        char* __restrict__ ws) {
    __shared__ __align__(16) char smem[SMEM_BYTES];
    cg::grid_group grid = cg::this_grid();
    const int j = threadIdx.x;
    WSMap W = make_ws(ws);

    for (int u = blockIdx.x; u < 96; u += NBLK) phase_decomp(u, smem, j, x, gw1, gw2, W);
    grid.sync();
    for (int u = blockIdx.x; u < 256; u += NBLK)
        gatemm_phase<128, 0>(u, smem, j, W.Xh, W.Xm, W.Xl, W.G1h, W.G1m, W.G1l,
                             gb1, nullptr, W.Hh, W.Hm, W.Hl);
    grid.sync();
    for (int u = blockIdx.x; u < 256; u += NBLK)
        gatemm_phase<512, 1>(u, smem, j, W.Hh, W.Hm, W.Hl, W.G2h, W.G2m, W.G2l,
                             gb2, W.h2, nullptr, nullptr, nullptr);
    grid.sync();
    for (int u = blockIdx.x; u < 128; u += NBLK) phase_gate3(u, smem, j, gw3, gb3, W);
    grid.sync();
    for (int u = blockIdx.x; u < NEXPERT; u += NBLK) phase_lists(u, smem, j, W);
    grid.sync();
    for (int u = blockIdx.x; u < 512; u += NBLK) phase_l1(u, smem, j, x, W1, B1, W);
    grid.sync();
    for (int u = blockIdx.x; u < 512; u += NBLK) phase_l2(u, smem, j, W2, W);
    grid.sync();
    for (int u = blockIdx.x; u < 512; u += NBLK) phase_combine(u, j, B2, out, W);
}

// ---------------- standalone fallback kernels (same bodies) ----------------
__global__ __launch_bounds__(256) void k_decomp(const float* x, const float* gw1,
                                                const float* gw2, char* ws) {
    __shared__ __align__(16) char smem[SMEM_BYTES];
    WSMap W = make_ws(ws);
    phase_decomp(blockIdx.x, smem, threadIdx.x, x, gw1, gw2, W);
}
__global__ __launch_bounds__(256) void k_gate1(const float* gb1, char* ws) {
    __shared__ __align__(16) char smem[SMEM_BYTES];
    WSMap W = make_ws(ws);
    gatemm_phase<128, 0>(blockIdx.x, smem, threadIdx.x, W.Xh, W.Xm, W.Xl,
                         W.G1h, W.G1m, W.G1l, gb1, nullptr, W.Hh, W.Hm, W.Hl);
}
__global__ __launch_bounds__(256) void k_gate2(const float* gb2, char* ws) {
    __shared__ __align__(16) char smem[SMEM_BYTES];
    WSMap W = make_ws(ws);
    gatemm_phase<512, 1>(blockIdx.x, smem, threadIdx.x, W.Hh, W.Hm, W.Hl,
                         W.G2h, W.G2m, W.G2l, gb2, W.h2, nullptr, nullptr, nullptr);
}
__global__ __launch_bounds__(256) void k_gate3(const float* gw3, const float* gb3,
                                               char* ws) {
    __shared__ __align__(16) char smem[SMEM_BYTES];
    WSMap W = make_ws(ws);
    phase_gate3(blockIdx.x, smem, threadIdx.x, gw3, gb3, W);
}
__global__ __launch_bounds__(256) void k_lists(char* ws) {
    __shared__ __align__(16) char smem[SMEM_BYTES];
    WSMap W = make_ws(ws);
    phase_lists(blockIdx.x, smem, threadIdx.x, W);
}
__global__ __launch_bounds__(256) void k_l1(const float* x, const float* W1,
                                            const float* B1, char* ws) {
    __shared__ __align__(16) char smem[SMEM_BYTES];
    WSMap W = make_ws(ws);
    phase_l1(blockIdx.x, smem, threadIdx.x, x, W1, B1, W);
}
__global__ __launch_bounds__(256) void k_l2(const float* W2, char* ws) {
    __shared__ __align__(16) char smem[SMEM_BYTES];
    WSMap W = make_ws(ws);
    phase_l2(blockIdx.x, smem, threadIdx.x, W2, W);
}
__global__ __launch_bounds__(256) void k_combine(const float* B2, float* out,
                                                 char* ws) {
    WSMap W = make_ws(ws);
    phase_combine(blockIdx.x, threadIdx.x, B2, out, W);
}

extern "C" void kernel_launch(void* const* d_in, const int* in_sizes, int n_in,
                              void* d_out, int out_size, void* d_ws, size_t ws_size,
                              hipStream_t stream) {
    const float* x   = (const float*)d_in[0];
    const float* gw1 = (const float*)d_in[1];
    const float* gb1 = (const float*)d_in[2];
    const float* gw2 = (const float*)d_in[3];
    const float* gb2 = (const float*)d_in[4];
    const float* gw3 = (const float*)d_in[5];
    const float* gb3 = (const float*)d_in[6];
    const float* W1  = (const float*)d_in[7];
    const float* B1  = (const float*)d_in[8];
    const float* W2  = (const float*)d_in[9];
    const float* B2  = (const float*)d_in[10];
    float* outp = (float*)d_out;
    char* wsp = (char*)d_ws;

    void* args[] = {(void*)&x, (void*)&gw1, (void*)&gb1, (void*)&gw2, (void*)&gb2,
                    (void*)&gw3, (void*)&gb3, (void*)&W1, (void*)&B1, (void*)&W2,
                    (void*)&B2, (void*)&outp, (void*)&wsp};
    hipError_t err = hipLaunchCooperativeKernel((const void*)moe_mega, dim3(NBLK),
                                                dim3(256), args, 0, stream);
    if (err != hipSuccess) {
        // deterministic fallback: same phase bodies as 8 ordered kernels
        k_decomp<<<dim3(96), 256, 0, stream>>>(x, gw1, gw2, wsp);
        k_gate1<<<dim3(256), 256, 0, stream>>>(gb1, wsp);
        k_gate2<<<dim3(256), 256, 0, stream>>>(gb2, wsp);
        k_gate3<<<dim3(128), 256, 0, stream>>>(gw3, gb3, wsp);
        k_lists<<<dim3(NEXPERT), 256, 0, stream>>>(wsp);
        k_l1<<<dim3(512), 256, 0, stream>>>(x, W1, B1, wsp);
        k_l2<<<dim3(512), 256, 0, stream>>>(W2, wsp);
        k_combine<<<dim3(512), 256, 0, stream>>>(B2, outp, wsp);
    }
}

// Round 11
// 62.831 us; speedup vs baseline: 4.3481x; 4.3481x over previous
//
#include <hip/hip_runtime.h>
#include <math.h>

#define NDIM 128
#define NHID 512
#define NEXPERT 64
#define NTOK 1024
#define NPAIR (NTOK * 2)

typedef __attribute__((ext_vector_type(8))) short short8_t;
typedef __attribute__((ext_vector_type(4))) float f32x4;

__device__ __forceinline__ float gelu_f(float v) {
    return 0.5f * v * (1.0f + erff(v * 0.7071067811865476f));
}
__device__ __forceinline__ unsigned short f2bf(float f) {
    union { float f; unsigned u; } v; v.f = f;
    unsigned r = v.u + 0x7FFFu + ((v.u >> 16) & 1u);
    return (unsigned short)(r >> 16);
}
__device__ __forceinline__ float bf2f(unsigned short h) {
    union { unsigned u; float f; } v; v.u = ((unsigned)h) << 16;
    return v.f;
}
__device__ __forceinline__ void split3(float f, short& ho, short& mo, short& lo) {
    const unsigned short h = f2bf(f);
    const float r1 = f - bf2f(h);
    const unsigned short m = f2bf(r1);
    const unsigned short l = f2bf(r1 - bf2f(m));
    ho = (short)h; mo = (short)m; lo = (short)l;
}

// ============ N1: gate1 (inline split of x,gw1) ∥ decomp(gw2) ============
// blocks [0,256): gate1 32m x 64n tiles -> H planes (bit-identical to R8 path)
// blocks [256,320): gw2 -> G2 planes transposed [n][k]
__global__ __launch_bounds__(256) void k_g1d2(
        const float* __restrict__ x, const float* __restrict__ gw1,
        const float* __restrict__ gw2, const float* __restrict__ gb1,
        unsigned short* __restrict__ G2h, unsigned short* __restrict__ G2m,
        unsigned short* __restrict__ G2l, unsigned short* __restrict__ Hh,
        unsigned short* __restrict__ Hm, unsigned short* __restrict__ Hl) {
    __shared__ __align__(16) char smem[58112];
    const int j = threadIdx.x;
    if (blockIdx.x >= 256) {
        // ---- decomp gw2 (64x64 tiles) ----
        float (*T)[65] = (float (*)[65])smem;
        const int u = blockIdx.x - 256;
        const int k0 = (u >> 3) * 64, n0 = (u & 7) * 64;
#pragma unroll
        for (int q = 0; q < 4; ++q) {
            const int idx = j + 256 * q;
            const int kr = idx >> 4, c4 = idx & 15;
            float4 v = *(const float4*)(gw2 + (size_t)(k0 + kr) * NHID + n0 + c4 * 4);
            T[kr][c4 * 4 + 0] = v.x; T[kr][c4 * 4 + 1] = v.y;
            T[kr][c4 * 4 + 2] = v.z; T[kr][c4 * 4 + 3] = v.w;
        }
        __syncthreads();
#pragma unroll
        for (int q = 0; q < 4; ++q) {
            const int idx = j + 256 * q;
            const int n = idx >> 4, k4 = idx & 15;
            short4 sh, sm, sl;
#pragma unroll
            for (int qq = 0; qq < 4; ++qq)
                split3(T[k4 * 4 + qq][n], (&sh.x)[qq], (&sm.x)[qq], (&sl.x)[qq]);
            const size_t o = (size_t)(n0 + n) * NHID + k0 + k4 * 4;
            *(short4*)(G2h + o) = sh;
            *(short4*)(G2m + o) = sm;
            *(short4*)(G2l + o) = sl;
        }
        return;
    }
    // ---- gate1 ----
    short (*Ahs)[32][72] = (short (*)[32][72])smem;
    short (*Bss)[64][72] = (short (*)[64][72])(smem + 13824);
    float (*T)[65] = (float (*)[65])(smem + 41472);
    const int u = blockIdx.x;
    const int m0 = (u >> 3) * 32, n0 = (u & 7) * 64;
    const int w = j >> 6, lane = j & 63;
    const int mt = w & 1, npair = w >> 1;
    const int lrow = lane & 15, lseg = lane >> 4;
    f32x4 acc[2];
    acc[0] = (f32x4){0.f, 0.f, 0.f, 0.f};
    acc[1] = (f32x4){0.f, 0.f, 0.f, 0.f};
    for (int kc = 0; kc < NDIM; kc += 64) {
        __syncthreads();
        // gw1 chunk [kc..kc+64) x [n0..n0+64) -> T (f32)
#pragma unroll
        for (int q = 0; q < 4; ++q) {
            const int idx = j + 256 * q;
            const int kr = idx >> 4, c4 = idx & 15;
            float4 v = *(const float4*)(gw1 + (size_t)(kc + kr) * NHID + n0 + c4 * 4);
            T[kr][c4 * 4 + 0] = v.x; T[kr][c4 * 4 + 1] = v.y;
            T[kr][c4 * 4 + 2] = v.z; T[kr][c4 * 4 + 3] = v.w;
        }
        // x chunk -> A planes (row-major, no transpose)
#pragma unroll
        for (int q = 0; q < 2; ++q) {
            const int idx = j + 256 * q;
            const int row = idx >> 4, c4 = idx & 15;
            float4 v = *(const float4*)(x + (size_t)(m0 + row) * NDIM + kc + c4 * 4);
            short4 sh, sm, sl;
#pragma unroll
            for (int qq = 0; qq < 4; ++qq)
                split3((&v.x)[qq], (&sh.x)[qq], (&sm.x)[qq], (&sl.x)[qq]);
            *(short4*)&Ahs[0][row][c4 * 4] = sh;
            *(short4*)&Ahs[1][row][c4 * 4] = sm;
            *(short4*)&Ahs[2][row][c4 * 4] = sl;
        }
        __syncthreads();
        // T -> B planes [n][k]
#pragma unroll
        for (int q = 0; q < 4; ++q) {
            const int idx = j + 256 * q;
            const int nn = idx >> 4, k4 = idx & 15;
            short4 sh, sm, sl;
#pragma unroll
            for (int qq = 0; qq < 4; ++qq)
                split3(T[k4 * 4 + qq][nn], (&sh.x)[qq], (&sm.x)[qq], (&sl.x)[qq]);
            *(short4*)&Bss[0][nn][k4 * 4] = sh;
            *(short4*)&Bss[1][nn][k4 * 4] = sm;
            *(short4*)&Bss[2][nn][k4 * 4] = sl;
        }
        __syncthreads();
#pragma unroll
        for (int ks = 0; ks < 2; ++ks) {
            const int ko = ks * 32 + lseg * 8;
            short8_t ah = *(short8_t*)&Ahs[0][mt * 16 + lrow][ko];
            short8_t am = *(short8_t*)&Ahs[1][mt * 16 + lrow][ko];
            short8_t al = *(short8_t*)&Ahs[2][mt * 16 + lrow][ko];
#pragma unroll
            for (int nt = 0; nt < 2; ++nt) {
                const int nr = (npair * 2 + nt) * 16 + lrow;
                short8_t bh = *(short8_t*)&Bss[0][nr][ko];
                short8_t bm = *(short8_t*)&Bss[1][nr][ko];
                short8_t bl = *(short8_t*)&Bss[2][nr][ko];
                acc[nt] = __builtin_amdgcn_mfma_f32_16x16x32_bf16(ah, bh, acc[nt], 0, 0, 0);
                acc[nt] = __builtin_amdgcn_mfma_f32_16x16x32_bf16(am, bh, acc[nt], 0, 0, 0);
                acc[nt] = __builtin_amdgcn_mfma_f32_16x16x32_bf16(ah, bm, acc[nt], 0, 0, 0);
                acc[nt] = __builtin_amdgcn_mfma_f32_16x16x32_bf16(al, bh, acc[nt], 0, 0, 0);
                acc[nt] = __builtin_amdgcn_mfma_f32_16x16x32_bf16(ah, bl, acc[nt], 0, 0, 0);
                acc[nt] = __builtin_amdgcn_mfma_f32_16x16x32_bf16(am, bm, acc[nt], 0, 0, 0);
            }
        }
    }
#pragma unroll
    for (int nt = 0; nt < 2; ++nt) {
        const int col = n0 + (npair * 2 + nt) * 16 + lrow;
        const float bb = gb1[col];
#pragma unroll
        for (int r = 0; r < 4; ++r) {
            const int row = m0 + mt * 16 + lseg * 4 + r;
            const float h = gelu_f(acc[nt][r] + bb);
            short hh, hm, hl;
            split3(h, hh, hm, hl);
            const size_t o = (size_t)row * NHID + col;
            Hh[o] = (unsigned short)hh; Hm[o] = (unsigned short)hm;
            Hl[o] = (unsigned short)hl;
        }
    }
}

// ============ N2: gate2 = gelu(h1 @ gw2 + gb2) -> h2 f32 ============
__global__ __launch_bounds__(256) void k_gate2(
        const unsigned short* __restrict__ Ahp, const unsigned short* __restrict__ Amp,
        const unsigned short* __restrict__ Alp,
        const unsigned short* __restrict__ Bhp, const unsigned short* __restrict__ Bmp,
        const unsigned short* __restrict__ Blp,
        const float* __restrict__ gb2, float* __restrict__ h2) {
    __shared__ short Ahs[3][32][72];
    __shared__ short Bss[3][64][72];
    const int j = threadIdx.x;
    const int u = blockIdx.x;
    const int m0 = (u >> 3) * 32, n0 = (u & 7) * 64;
    const int w = j >> 6, lane = j & 63;
    const int mt = w & 1, npair = w >> 1;
    const int lrow = lane & 15, lseg = lane >> 4;
    const int K = NHID;
    f32x4 acc[2];
    acc[0] = (f32x4){0.f, 0.f, 0.f, 0.f};
    acc[1] = (f32x4){0.f, 0.f, 0.f, 0.f};
    for (int kc = 0; kc < K; kc += 64) {
        __syncthreads();
        {
            const int row = j >> 3, c8 = j & 7;
            const size_t o = (size_t)(m0 + row) * K + kc + c8 * 8;
            *(short8_t*)&Ahs[0][row][c8 * 8] = *(const short8_t*)(Ahp + o);
            *(short8_t*)&Ahs[1][row][c8 * 8] = *(const short8_t*)(Amp + o);
            *(short8_t*)&Ahs[2][row][c8 * 8] = *(const short8_t*)(Alp + o);
        }
#pragma unroll
        for (int q = 0; q < 2; ++q) {
            const int idx = j + 256 * q;
            const int nr = idx >> 3, c8 = idx & 7;
            const size_t o = (size_t)(n0 + nr) * K + kc + c8 * 8;
            *(short8_t*)&Bss[0][nr][c8 * 8] = *(const short8_t*)(Bhp + o);
            *(short8_t*)&Bss[1][nr][c8 * 8] = *(const short8_t*)(Bmp + o);
            *(short8_t*)&Bss[2][nr][c8 * 8] = *(const short8_t*)(Blp + o);
        }
        __syncthreads();
#pragma unroll
        for (int ks = 0; ks < 2; ++ks) {
            const int ko = ks * 32 + lseg * 8;
            short8_t ah = *(short8_t*)&Ahs[0][mt * 16 + lrow][ko];
            short8_t am = *(short8_t*)&Ahs[1][mt * 16 + lrow][ko];
            short8_t al = *(short8_t*)&Ahs[2][mt * 16 + lrow][ko];
#pragma unroll
            for (int nt = 0; nt < 2; ++nt) {
                const int nr = (npair * 2 + nt) * 16 + lrow;
                short8_t bh = *(short8_t*)&Bss[0][nr][ko];
                short8_t bm = *(short8_t*)&Bss[1][nr][ko];
                short8_t bl = *(short8_t*)&Bss[2][nr][ko];
                acc[nt] = __builtin_amdgcn_mfma_f32_16x16x32_bf16(ah, bh, acc[nt], 0, 0, 0);
                acc[nt] = __builtin_amdgcn_mfma_f32_16x16x32_bf16(am, bh, acc[nt], 0, 0, 0);
                acc[nt] = __builtin_amdgcn_mfma_f32_16x16x32_bf16(ah, bm, acc[nt], 0, 0, 0);
                acc[nt] = __builtin_amdgcn_mfma_f32_16x16x32_bf16(al, bh, acc[nt], 0, 0, 0);
                acc[nt] = __builtin_amdgcn_mfma_f32_16x16x32_bf16(ah, bl, acc[nt], 0, 0, 0);
                acc[nt] = __builtin_amdgcn_mfma_f32_16x16x32_bf16(am, bm, acc[nt], 0, 0, 0);
            }
        }
    }
#pragma unroll
    for (int nt = 0; nt < 2; ++nt) {
        const int col = n0 + (npair * 2 + nt) * 16 + lrow;
        const float bb = gb2[col];
#pragma unroll
        for (int r = 0; r < 4; ++r) {
            const int row = m0 + mt * 16 + lseg * 4 + r;
            h2[(size_t)row * NHID + col] = gelu_f(acc[nt][r] + bb);
        }
    }
}

// ============ N3: gate3 (128 blocks x 8 tokens) ============
__global__ __launch_bounds__(256) void k_gate3(
        const float* __restrict__ h2, const float* __restrict__ gw3,
        const float* __restrict__ gb3, int* __restrict__ eidx,
        float* __restrict__ wval) {
    __shared__ float hs[8][132];
    __shared__ float gs[128][72];
    const int j = threadIdx.x;
    const int lane = j & 63;
    const int w = j >> 6;
    const int t0 = blockIdx.x * 8;
    float acc[2] = {0.f, 0.f};
    for (int k0 = 0; k0 < NHID; k0 += 128) {
        __syncthreads();
        {
            const int tok = j >> 5, c4 = j & 31;
            *(float4*)&hs[tok][c4 * 4] =
                *(const float4*)(h2 + (size_t)(t0 + tok) * NHID + k0 + c4 * 4);
        }
#pragma unroll
        for (int q = 0; q < 8; ++q) {
            const int idx = j + 256 * q;
            const int kk = idx >> 4, c4 = idx & 15;
            *(float4*)&gs[kk][c4 * 4] =
                *(const float4*)(gw3 + (size_t)(k0 + kk) * NEXPERT + c4 * 4);
        }
        __syncthreads();
        for (int kk = 0; kk < 128; ++kk) {
            const float g = gs[kk][lane];
            acc[0] += hs[w * 2][kk] * g;
            acc[1] += hs[w * 2 + 1][kk] * g;
        }
    }
    const float bias = gb3[lane];
#pragma unroll
    for (int i = 0; i < 2; ++i) {
        const int t = t0 + w * 2 + i;
        float s = 1.f / (1.f + expf(-(acc[i] + bias)));
        float v = s; int ix = lane;
#pragma unroll
        for (int off = 32; off >= 1; off >>= 1) {
            float ov = __shfl_xor(v, off);
            int oi = __shfl_xor(ix, off);
            if (ov > v || (ov == v && oi < ix)) { v = ov; ix = oi; }
        }
        const float v0 = v; const int i0 = ix;
        float v2 = (lane == i0) ? -1.f : s; int ix2 = lane;
#pragma unroll
        for (int off = 32; off >= 1; off >>= 1) {
            float ov = __shfl_xor(v2, off);
            int oi = __shfl_xor(ix2, off);
            if (ov > v2 || (ov == v2 && oi < ix2)) { v2 = ov; ix2 = oi; }
        }
        if (lane == 0) {
            float inv = 1.f / (v0 + v2);
            eidx[t * 2] = i0;  eidx[t * 2 + 1] = ix2;
            wval[t * 2] = v0 * inv;  wval[t * 2 + 1] = v2 * inv;
        }
    }
}

// deterministic in-block list build (index-ascending; identical in all blocks
// of the same expert). Waves own disjoint 512-entry ranges; ballot-scan.
__device__ __forceinline__ int build_list(
        const int* __restrict__ eidx, int e, int lane, int w,
        int* lst, int* wtot) {
    unsigned long long msk[8];
    const int b0 = w * 512;
    int tot = 0;
#pragma unroll
    for (int c = 0; c < 8; ++c) {
        const int i = b0 + c * 64 + lane;
        msk[c] = __ballot(eidx[i] == e);
        tot += (int)__popcll(msk[c]);
    }
    if (lane == 0) wtot[w] = tot;
    __syncthreads();
    int woff = 0;
    for (int q = 0; q < w; ++q) woff += wtot[q];
    int run = 0;
#pragma unroll
    for (int c = 0; c < 8; ++c) {
        const int i = b0 + c * 64 + lane;
        if ((msk[c] >> lane) & 1ull)
            lst[woff + run + (int)__popcll(msk[c] & ((1ull << lane) - 1ull))] = i;
        run += (int)__popcll(msk[c]);
    }
    const int n = wtot[0] + wtot[1] + wtot[2] + wtot[3];
    __syncthreads();
    return n;
}

// ============ N4: expert layer1 (bf16 MFMA) + in-block lists ============
__global__ __launch_bounds__(256) void k_l1(
        const float* __restrict__ x, const float* __restrict__ W1,
        const float* __restrict__ B1, const int* __restrict__ eidx,
        unsigned short* __restrict__ tbuf) {
    __shared__ short As_[32 * 136];
    __shared__ short Bs_[64 * 136];
    __shared__ int prs[32];
    __shared__ int wtot[4];
    __shared__ int lst[NPAIR];
    const int j = threadIdx.x;
    const int lane = j & 63;
    const int w = j >> 6;
    const int e = blockIdx.x >> 3;
    const int f0 = (blockIdx.x & 7) * 64;
    char* Asc = (char*)As_;
    char* Bsc = (char*)Bs_;
    const int n = build_list(eidx, e, lane, w, lst, wtot);
    const float* W1e = W1 + (size_t)e * NHID * NDIM;
    for (int idx = j; idx < 2048; idx += 256) {
        const int f = idx >> 5, c4 = idx & 31;
        float4 v = *(const float4*)(W1e + (size_t)(f0 + f) * NDIM + c4 * 4);
        short4 s; s.x = (short)f2bf(v.x); s.y = (short)f2bf(v.y);
        s.z = (short)f2bf(v.z); s.w = (short)f2bf(v.w);
        *(short4*)(Bsc + f * 272 + c4 * 8) = s;
    }
    const float bbias = B1[e * NHID + f0 + w * 16 + (lane & 15)];
    for (int bt = 0; bt * 32 < n; ++bt) {
        __syncthreads();
        if (j < 32) prs[j] = (bt * 32 + j < n) ? lst[bt * 32 + j] : -1;
        __syncthreads();
        for (int idx = j; idx < 1024; idx += 256) {
            const int tok = idx >> 5, c4 = idx & 31;
            const int pr = prs[tok];
            float4 v = make_float4(0.f, 0.f, 0.f, 0.f);
            if (pr >= 0) v = ((const float4*)x)[(size_t)(pr >> 1) * 32 + c4];
            short4 s; s.x = (short)f2bf(v.x); s.y = (short)f2bf(v.y);
            s.z = (short)f2bf(v.z); s.w = (short)f2bf(v.w);
            *(short4*)(Asc + tok * 272 + c4 * 8) = s;
        }
        __syncthreads();
        f32x4 acc[2];
        acc[0] = (f32x4){0.f, 0.f, 0.f, 0.f};
        acc[1] = (f32x4){0.f, 0.f, 0.f, 0.f};
        const int acol = ((lane >> 4) << 4);
        const int brow = w * 16 + (lane & 15);
#pragma unroll
        for (int ks = 0; ks < 4; ++ks) {
            short8_t b = *(short8_t*)(Bsc + brow * 272 + ks * 64 + acol);
#pragma unroll
            for (int mt = 0; mt < 2; ++mt) {
                short8_t a = *(short8_t*)(Asc + (mt * 16 + (lane & 15)) * 272 + ks * 64 + acol);
                acc[mt] = __builtin_amdgcn_mfma_f32_16x16x32_bf16(a, b, acc[mt], 0, 0, 0);
            }
        }
        const int fcol = f0 + w * 16 + (lane & 15);
#pragma unroll
        for (int mt = 0; mt < 2; ++mt) {
#pragma unroll
            for (int r = 0; r < 4; ++r) {
                const int tok = mt * 16 + ((lane >> 4) << 2) + r;
                const int pr = prs[tok];
                if (pr >= 0)
                    tbuf[(size_t)pr * NHID + fcol] = f2bf(gelu_f(acc[mt][r] + bbias));
            }
        }
    }
}

// ============ N5: expert layer2 (bf16 MFMA, split-K=4) + in-block lists ======
__global__ __launch_bounds__(256) void k_l2(
        const float* __restrict__ W2, const int* __restrict__ eidx,
        const unsigned short* __restrict__ tbuf, float* __restrict__ pbuf) {
    __shared__ short As_[32 * 136];
    __shared__ short Bs_[64 * 136];
    __shared__ int prs[32];
    __shared__ int wtot[4];
    __shared__ int lst[NPAIR];
    const int j = threadIdx.x;
    const int lane = j & 63;
    const int w = j >> 6;
    const int e = blockIdx.x >> 3;
    const int d0 = ((blockIdx.x >> 2) & 1) * 64;
    const int kz = blockIdx.x & 3;
    const int k0 = kz * 128;
    char* Asc = (char*)As_;
    char* Bsc = (char*)Bs_;
    const int n = build_list(eidx, e, lane, w, lst, wtot);
    const float* W2e = W2 + (size_t)e * NDIM * NHID;
    for (int idx = j; idx < 2048; idx += 256) {
        const int d = idx >> 5, c4 = idx & 31;
        float4 v = *(const float4*)(W2e + (size_t)(d0 + d) * NHID + k0 + c4 * 4);
        short4 s; s.x = (short)f2bf(v.x); s.y = (short)f2bf(v.y);
        s.z = (short)f2bf(v.z); s.w = (short)f2bf(v.w);
        *(short4*)(Bsc + d * 272 + c4 * 8) = s;
    }
    float* pz = pbuf + (size_t)kz * NPAIR * NDIM;
    for (int bt = 0; bt * 32 < n; ++bt) {
        __syncthreads();
        if (j < 32) prs[j] = (bt * 32 + j < n) ? lst[bt * 32 + j] : -1;
        __syncthreads();
        for (int idx = j; idx < 512; idx += 256) {
            const int tok = idx >> 4, c8 = idx & 15;
            const int pr = prs[tok];
            short8_t v = (short8_t)(short)0;
            if (pr >= 0) v = *(const short8_t*)(tbuf + (size_t)pr * NHID + k0 + c8 * 8);
            *(short8_t*)(Asc + tok * 272 + c8 * 16) = v;
        }
        __syncthreads();
        f32x4 acc[2];
        acc[0] = (f32x4){0.f, 0.f, 0.f, 0.f};
        acc[1] = (f32x4){0.f, 0.f, 0.f, 0.f};
        const int acol = ((lane >> 4) << 4);
        const int brow = w * 16 + (lane & 15);
#pragma unroll
        for (int ks = 0; ks < 4; ++ks) {
            short8_t b = *(short8_t*)(Bsc + brow * 272 + ks * 64 + acol);
#pragma unroll
            for (int mt = 0; mt < 2; ++mt) {
                short8_t a = *(short8_t*)(Asc + (mt * 16 + (lane & 15)) * 272 + ks * 64 + acol);
                acc[mt] = __builtin_amdgcn_mfma_f32_16x16x32_bf16(a, b, acc[mt], 0, 0, 0);
            }
        }
        const int dcol = d0 + w * 16 + (lane & 15);
#pragma unroll
        for (int mt = 0; mt < 2; ++mt) {
#pragma unroll
            for (int r = 0; r < 4; ++r) {
                const int tok = mt * 16 + ((lane >> 4) << 2) + r;
                const int pr = prs[tok];
                if (pr >= 0) pz[(size_t)pr * NDIM + dcol] = acc[mt][r];
            }
        }
    }
}

// ============ N6: combine ============
__global__ __launch_bounds__(256) void k_combine(
        const float* __restrict__ pbuf, const float* __restrict__ wval,
        const int* __restrict__ eidx, const float* __restrict__ B2,
        float* __restrict__ out) {
    const int i = blockIdx.x * 256 + threadIdx.x;
    const int t = i >> 7, d = i & (NDIM - 1);
    const int KS = NPAIR * NDIM;
    float y[2];
#pragma unroll
    for (int k = 0; k < 2; ++k) {
        const int p = t * 2 + k;
        float s = pbuf[p * NDIM + d] + pbuf[KS + p * NDIM + d]
                + pbuf[2 * KS + p * NDIM + d] + pbuf[3 * KS + p * NDIM + d]
                + B2[eidx[p] * NDIM + d];
        y[k] = gelu_f(s);
    }
    out[i] = wval[t * 2] * y[0] + wval[t * 2 + 1] * y[1];
}

extern "C" void kernel_launch(void* const* d_in, const int* in_sizes, int n_in,
                              void* d_out, int out_size, void* d_ws, size_t ws_size,
                              hipStream_t stream) {
    const float* x   = (const float*)d_in[0];
    const float* gw1 = (const float*)d_in[1];
    const float* gb1 = (const float*)d_in[2];
    const float* gw2 = (const float*)d_in[3];
    const float* gb2 = (const float*)d_in[4];
    const float* gw3 = (const float*)d_in[5];
    const float* gb3 = (const float*)d_in[6];
    const float* W1  = (const float*)d_in[7];
    const float* B1  = (const float*)d_in[8];
    const float* W2  = (const float*)d_in[9];
    const float* B2  = (const float*)d_in[10];
    float* out = (float*)d_out;
    char* ws = (char*)d_ws;

    // G2 planes [0,1.5M) | H planes [1.5M,4.5M) | h2 [4.5M,6.5M) |
    // tbuf [0,2M) (aliases G2+Hh-head, dead after N2) |
    // pbuf [2M,6M) (aliases Hm/Hl/h2-head, dead after N2/N3) | ctrl [7M..)
    unsigned short* G2h = (unsigned short*)(ws);
    unsigned short* G2m = (unsigned short*)(ws + 524288);
    unsigned short* G2l = (unsigned short*)(ws + 1048576);
    unsigned short* Hh  = (unsigned short*)(ws + 1572864);
    unsigned short* Hm  = (unsigned short*)(ws + 2621440);
    unsigned short* Hl  = (unsigned short*)(ws + 3670016);
    float*          h2  = (float*)(ws + 4718592);
    unsigned short* tbuf = (unsigned short*)(ws);
    float*          pbuf = (float*)(ws + 2097152);
    int*   eidx = (int*)  (ws + 7340032);
    float* wval = (float*)(ws + 7340032 + 8192);

    k_g1d2<<<dim3(320), 256, 0, stream>>>(x, gw1, gw2, gb1, G2h, G2m, G2l, Hh, Hm, Hl);
    k_gate2<<<dim3(256), 256, 0, stream>>>(Hh, Hm, Hl, G2h, G2m, G2l, gb2, h2);
    k_gate3<<<dim3(128), 256, 0, stream>>>(h2, gw3, gb3, eidx, wval);
    k_l1<<<dim3(512), 256, 0, stream>>>(x, W1, B1, eidx, tbuf);
    k_l2<<<dim3(512), 256, 0, stream>>>(W2, eidx, tbuf, pbuf);
    k_combine<<<dim3(512), 256, 0, stream>>>(pbuf, wval, eidx, B2, out);
}